// Round 1
// baseline (481.402 us; speedup 1.0000x reference)
//
#include <hip/hip_runtime.h>
#include <hip/hip_bf16.h>

#define NF 2
#define NLOC 4096
#define NALL 8192
#define NNEI_ 138

__device__ __forceinline__ float fast_tanh(float a) {
#if __has_builtin(__builtin_amdgcn_exp2f) && __has_builtin(__builtin_amdgcn_rcpf)
    float t = __builtin_amdgcn_exp2f(a * 2.885390081777927f);  // exp(2a)
    return 1.0f - 2.0f * __builtin_amdgcn_rcpf(t + 1.0f);
#else
    float t = exp2f(a * 2.885390081777927f);
    return 1.0f - 2.0f / (t + 1.0f);
#endif
}

// ws[0..2499]      : w1T [2][50][25]  (j-major, k contiguous)
// ws[2500..12499]  : w2T [2][100][50] (c-major, j contiguous)
__global__ void transpose_weights(const float* __restrict__ w1,
                                  const float* __restrict__ w2,
                                  float* __restrict__ ws) {
    int i = threadIdx.x + blockIdx.x * blockDim.x;
    if (i < 2500) {
        int t = i / 1250, r = i % 1250;
        int j = r / 25, k = r % 25;
        ws[i] = w1[t * 1250 + k * 50 + j];
    }
    if (i < 10000) {
        int t = i / 5000, r = i % 5000;
        int c = r / 50, j = r % 50;
        ws[2500 + i] = w2[t * 5000 + j * 100 + c];
    }
}

__global__ __launch_bounds__(64) void descr_main(
    const float* __restrict__ coord, const int* __restrict__ atype,
    const int* __restrict__ nlist, const float* __restrict__ mean,
    const float* __restrict__ stddev, const float* __restrict__ w0,
    const float* __restrict__ b0, const float* __restrict__ b1,
    const float* __restrict__ b2, const float* __restrict__ w1T,
    const float* __restrict__ w2T, float* __restrict__ out_res,
    float* __restrict__ out_sw)
{
    const int b = blockIdx.x;       // flat (frame, local atom)
    const int f = b >> 12;
    const int il = b & 4095;
    const int lane = threadIdx.x;   // 0..63

    // wave-uniform center data (scalar loads)
    const float cx = coord[(f * NALL + il) * 3 + 0];
    const float cy = coord[(f * NALL + il) * 3 + 1];
    const float cz = coord[(f * NALL + il) * 3 + 2];
    const int aty = atype[f * NALL + il];

    float out_lo = 0.0f;  // channel sums: lane L holds channel L
    float out_hi = 0.0f;  // lane L holds channel 64+L (L<36)

    for (int p = 0; p < 3; ++p) {
        int t, n0, cnt;
        if (p == 0)      { t = 0; n0 = 0;   cnt = 46; }
        else if (p == 1) { t = 1; n0 = 46;  cnt = 64; }
        else             { t = 1; n0 = 110; cnt = 28; }

        const bool active = lane < cnt;
        const int n = n0 + lane;

        // ---- phase A: environment scalar s, write sw ----
        float s = 0.0f;
        if (active) {
            int jn = nlist[b * NNEI_ + n];
            bool m = jn >= 0;
            int jj = m ? jn : 0;
            float dx = coord[(f * NALL + jj) * 3 + 0] - cx;
            float dy = coord[(f * NALL + jj) * 3 + 1] - cy;
            float dz = coord[(f * NALL + jj) * 3 + 2] - cz;
            float lsq = dx * dx + dy * dy + dz * dz;
            float len = sqrtf(m ? lsq : 1.0f);
            float uu = (len - 0.5f) * (1.0f / 5.5f);
            float vv = uu * uu * uu * (uu * (-6.0f * uu + 15.0f) - 10.0f) + 1.0f;
            float sw = (len <= 0.5f) ? 1.0f : ((len >= 6.0f) ? 0.0f : vv);
            if (!m) sw = 0.0f;
            out_sw[b * NNEI_ + n] = sw;
            float env = sw / len;
            s = (env - mean[aty * NNEI_ + n]) / stddev[aty * NNEI_ + n];
        }

        // ---- layer 0: x[25] = tanh(s*w0 + b0) ----
        float x[25];
        const float* w0t = w0 + t * 25;
        const float* b0t = b0 + t * 25;
#pragma unroll
        for (int k = 0; k < 25; ++k)
            x[k] = fast_tanh(s * w0t[k] + b0t[k]);

        // ---- layer 1: x2[50] = tanh(x@w1 + b1) + x[j%25] ----
        float x2[50];
        const float* w1t = w1T + t * 1250;
        const float* b1t = b1 + t * 50;
#pragma unroll
        for (int j = 0; j < 50; ++j) {
            float acc = b1t[j];
            const float* wr = w1t + j * 25;
#pragma unroll
            for (int k = 0; k < 25; ++k) acc += x[k] * wr[k];
            x2[j] = fast_tanh(acc) + x[(j < 25) ? j : (j - 25)];
        }

        // ---- residual channel sums: channel c gets sum_n x2[n][c%50] ----
#pragma unroll
        for (int j = 0; j < 50; ++j) {
            float v = active ? x2[j] : 0.0f;
#pragma unroll
            for (int off = 32; off > 0; off >>= 1) v += __shfl_xor(v, off);
            out_lo += (lane == j) ? v : 0.0f;           // channel j (<64)
            if (j + 50 < 64) out_lo += (lane == (j + 50)) ? v : 0.0f;
            else             out_hi += (lane == (j - 14)) ? v : 0.0f;  // channel j+50
        }

        // ---- layer 2 tanh part: channel c gets sum_n tanh(x2[n]@w2[:,c] + b2[c]) ----
        const float* w2t = w2T + t * 5000;
        const float* b2t = b2 + t * 100;
        for (int c = 0; c < 100; ++c) {
            float acc = b2t[c];
            const float* wr = w2t + c * 50;  // wave-uniform -> s_load
#pragma unroll
            for (int j = 0; j < 50; ++j) acc += x2[j] * wr[j];
            float val = active ? fast_tanh(acc) : 0.0f;
#pragma unroll
            for (int off = 32; off > 0; off >>= 1) val += __shfl_xor(val, off);
            if (c < 64) out_lo += (lane == c) ? val : 0.0f;
            else        out_hi += (lane == (c - 64)) ? val : 0.0f;
        }
    }

    const float sc = 0.2f / 138.0f;  // RES_RESCALE * (1/NNEI)
    out_res[b * 100 + lane] = out_lo * sc;
    if (lane < 36) out_res[b * 100 + 64 + lane] = out_hi * sc;
}

extern "C" void kernel_launch(void* const* d_in, const int* in_sizes, int n_in,
                              void* d_out, int out_size, void* d_ws, size_t ws_size,
                              hipStream_t stream) {
    const float* coord  = (const float*)d_in[0];
    const int*   atype  = (const int*)d_in[1];
    const int*   nlist  = (const int*)d_in[2];
    const float* mean   = (const float*)d_in[3];
    const float* stddev = (const float*)d_in[4];
    const float* w0 = (const float*)d_in[5];
    const float* b0 = (const float*)d_in[6];
    const float* w1 = (const float*)d_in[7];
    const float* b1 = (const float*)d_in[8];
    const float* w2 = (const float*)d_in[9];
    const float* b2 = (const float*)d_in[10];

    float* ws = (float*)d_ws;
    float* out_res = (float*)d_out;                 // [2][4096][100]
    float* out_sw  = out_res + NF * NLOC * 100;     // [2][4096][138]

    hipLaunchKernelGGL(transpose_weights, dim3(40), dim3(256), 0, stream, w1, w2, ws);
    hipLaunchKernelGGL(descr_main, dim3(NF * NLOC), dim3(64), 0, stream,
                       coord, atype, nlist, mean, stddev, w0, b0, b1, b2,
                       ws /*w1T*/, ws + 2500 /*w2T*/, out_res, out_sw);
}

// Round 2
// 126.159 us; speedup vs baseline: 3.8158x; 3.8158x over previous
//
#include <hip/hip_runtime.h>
#include <hip/hip_bf16.h>

typedef unsigned short u16;
typedef __attribute__((ext_vector_type(8))) short short8v;
typedef __attribute__((ext_vector_type(4))) float float4v;

#define NF 2
#define NLOC 4096
#define NALL 8192
#define NNEI_ 138

__device__ __forceinline__ float fast_tanh(float a) {
#if __has_builtin(__builtin_amdgcn_exp2f) && __has_builtin(__builtin_amdgcn_rcpf)
    float t = __builtin_amdgcn_exp2f(a * 2.885390081777927f);  // exp(2a)
    return 1.0f - 2.0f * __builtin_amdgcn_rcpf(t + 1.0f);
#else
    float t = exp2f(a * 2.885390081777927f);
    return 1.0f - 2.0f / (t + 1.0f);
#endif
}

__device__ __forceinline__ u16 f2bf(float x) {
    __hip_bfloat16 h = __float2bfloat16(x);
    return *reinterpret_cast<u16*>(&h);
}

// Pack weights into MFMA B-fragment order (bf16), zero-padded.
// B1: [2 types][4 ntiles][64 lanes][8 elems]   (K=25->32, N=50->64)
// B2: [2 types][2 ktiles][7 ntiles][64][8]     (K=50->64, N=100->112)
__global__ void prep_weights(const float* __restrict__ w1, const float* __restrict__ w2,
                             __hip_bfloat16* __restrict__ wsbf) {
    int i = threadIdx.x + blockIdx.x * blockDim.x;
    if (i < 4096) {
        int e = i & 7, lane = (i >> 3) & 63, nt = (i >> 9) & 3, t = i >> 11;
        int k = (lane >> 4) * 8 + e, j = nt * 16 + (lane & 15);
        float v = (k < 25 && j < 50) ? w1[t * 1250 + k * 50 + j] : 0.0f;
        wsbf[i] = __float2bfloat16(v);
    } else if (i < 4096 + 14336) {
        int j2 = i - 4096;
        int e = j2 & 7, lane = (j2 >> 3) & 63;
        int q = j2 >> 9;
        int nt = q % 7, kt = (q / 7) & 1, t = q / 14;
        int k = kt * 32 + (lane >> 4) * 8 + e, j = nt * 16 + (lane & 15);
        float v = (k < 50 && j < 100) ? w2[t * 5000 + k * 100 + j] : 0.0f;
        wsbf[4096 + j2] = __float2bfloat16(v);
    }
}

// Block = 1 atom. Rows: 0-47 = type0 neighbors 0-45 (+2 pad), wave 0.
//                  48-143 = type1 neighbors 46-137 (+4 pad), waves 1-3 (32 rows each).
__global__ __launch_bounds__(256, 2) void descr_mfma(
    const float* __restrict__ coord, const int* __restrict__ atype,
    const int* __restrict__ nlist, const float* __restrict__ mean,
    const float* __restrict__ stddev,
    const float* __restrict__ w0, const float* __restrict__ b0,
    const float* __restrict__ b1, const float* __restrict__ b2,
    const __hip_bfloat16* __restrict__ B1f, const __hip_bfloat16* __restrict__ B2f,
    float* __restrict__ out_res, float* __restrict__ out_sw)
{
    __shared__ __align__(16) u16 X[144 * 32];   // row-major, 16B-slot XOR swizzle
    __shared__ __align__(8)  u16 X2[64 * 150];  // col-major, stride 150 (bank-perfect reads)
    __shared__ float sS[144];
    __shared__ float psum[4][112];
    __shared__ float s2w[4][64];
    __shared__ float S2m[64];

    const int b = blockIdx.x, f = b >> 12, il = b & 4095;
    const int tid = threadIdx.x, wave = tid >> 6, lane = tid & 63;
    const int t = wave ? 1 : 0;
    const int row_base = wave ? (48 + 32 * (wave - 1)) : 0;
    const int n_rows = wave ? 32 : 48;
    const int mtiles = wave ? 2 : 3;
    const int vlimit = (wave == 0) ? 46 : ((wave == 3) ? 28 : 32);
    const int m = lane & 15, qt = lane >> 4;

    const int aty = atype[f * NALL + il];
    const float cx = coord[(f * NALL + il) * 3 + 0];
    const float cy = coord[(f * NALL + il) * 3 + 1];
    const float cz = coord[(f * NALL + il) * 3 + 2];

    // ---------------- phase A: s, sw, X staging ----------------
    {
        float s = 0.0f;
        const int row = row_base + lane;
        if (lane < vlimit) {
            const int n = wave ? (row - 2) : row;   // neighbor slot 0..137
            int jn = nlist[b * NNEI_ + n];
            float sw = 0.0f, env = 0.0f;
            if (jn >= 0) {
                float dx = coord[(f * NALL + jn) * 3 + 0] - cx;
                float dy = coord[(f * NALL + jn) * 3 + 1] - cy;
                float dz = coord[(f * NALL + jn) * 3 + 2] - cz;
                float len = sqrtf(dx * dx + dy * dy + dz * dz);
                float uu = (len - 0.5f) * (1.0f / 5.5f);
                float vv = uu * uu * uu * (uu * (-6.0f * uu + 15.0f) - 10.0f) + 1.0f;
                sw = (len <= 0.5f) ? 1.0f : ((len >= 6.0f) ? 0.0f : vv);
                env = sw / len;
            }
            out_sw[b * NNEI_ + n] = sw;
            s = (env - mean[aty * NNEI_ + n]) / stddev[aty * NNEI_ + n];
        }
        if (lane < n_rows) {
            sS[row] = s;
            unsigned int xp[16];
#pragma unroll
            for (int kk = 0; kk < 16; ++kk) {
                float v0 = (2 * kk < 25) ? fast_tanh(s * w0[t * 25 + 2 * kk] + b0[t * 25 + 2 * kk]) : 0.0f;
                float v1 = (2 * kk + 1 < 25) ? fast_tanh(s * w0[t * 25 + 2 * kk + 1] + b0[t * 25 + 2 * kk + 1]) : 0.0f;
                xp[kk] = (unsigned int)f2bf(v0) | ((unsigned int)f2bf(v1) << 16);
            }
#pragma unroll
            for (int sl = 0; sl < 4; ++sl) {
                int slot = sl ^ (row & 3);
                uint4 v = make_uint4(xp[4 * sl], xp[4 * sl + 1], xp[4 * sl + 2], xp[4 * sl + 3]);
                *reinterpret_cast<uint4*>(reinterpret_cast<char*>(X) + row * 64 + slot * 16) = v;
            }
        }
    }

    // ---------------- per-lane constants & B fragments ----------------
    float b1v[4], w0v[4], b0v[4], b2v[7];
#pragma unroll
    for (int nt = 0; nt < 4; ++nt) {
        int col = nt * 16 + m;
        b1v[nt] = (col < 50) ? b1[t * 50 + col] : 0.0f;
        int cm = (col < 25) ? col : (col - 25);
        if (col >= 50) cm = 0;
        w0v[nt] = w0[t * 25 + cm];
        b0v[nt] = b0[t * 25 + cm];
    }
#pragma unroll
    for (int nt = 0; nt < 7; ++nt) {
        int col = nt * 16 + m;
        b2v[nt] = (col < 100) ? b2[t * 100 + col] : 0.0f;
    }
    short8v B1g[4], B2g[2][7];
#pragma unroll
    for (int nt = 0; nt < 4; ++nt)
        B1g[nt] = *(const short8v*)(B1f + ((t * 4 + nt) * 64 + lane) * 8);
#pragma unroll
    for (int kt = 0; kt < 2; ++kt)
#pragma unroll
        for (int nt = 0; nt < 7; ++nt)
            B2g[kt][nt] = *(const short8v*)(B2f + (((t * 2 + kt) * 7 + nt) * 64 + lane) * 8);

    float psumr[7] = {0, 0, 0, 0, 0, 0, 0};
    float s2r[4] = {0, 0, 0, 0};

    // ---------------- main loop over M-tiles (wave-local) ----------------
#pragma unroll
    for (int mt = 0; mt < 3; ++mt) {
        if (mt >= mtiles) break;
        const int rbase = mt * 16;

        // L1: A-frag from X (swizzled), 4 MFMA
        const int arow = row_base + rbase + m;
        const int slot = qt ^ (arow & 3);
        short8v a1 = *(const short8v*)(reinterpret_cast<const char*>(X) + arow * 64 + slot * 16);
        float4v C1[4];
#pragma unroll
        for (int nt = 0; nt < 4; ++nt)
            C1[nt] = __builtin_amdgcn_mfma_f32_16x16x32_bf16(a1, B1g[nt], (float4v){0.f, 0.f, 0.f, 0.f}, 0, 0, 0);

        // x2 = tanh(C1+b1) + x (recomputed f32-exact), stage to X2 (col-major)
        float sr[4];
#pragma unroll
        for (int r = 0; r < 4; ++r) sr[r] = sS[row_base + rbase + qt * 4 + r];
#pragma unroll
        for (int nt = 0; nt < 4; ++nt) {
            const int col = nt * 16 + m;
            u16 p0, p1, p2, p3;
            {
                float v0 = 0.f, v1 = 0.f, v2 = 0.f, v3 = 0.f;
                if (col < 50) {
                    v0 = fast_tanh(C1[nt][0] + b1v[nt]) + fast_tanh(sr[0] * w0v[nt] + b0v[nt]);
                    v1 = fast_tanh(C1[nt][1] + b1v[nt]) + fast_tanh(sr[1] * w0v[nt] + b0v[nt]);
                    v2 = fast_tanh(C1[nt][2] + b1v[nt]) + fast_tanh(sr[2] * w0v[nt] + b0v[nt]);
                    v3 = fast_tanh(C1[nt][3] + b1v[nt]) + fast_tanh(sr[3] * w0v[nt] + b0v[nt]);
                }
                const int lr0 = rbase + qt * 4;
                s2r[nt] += ((lr0 + 0 < vlimit) ? v0 : 0.f) + ((lr0 + 1 < vlimit) ? v1 : 0.f) +
                           ((lr0 + 2 < vlimit) ? v2 : 0.f) + ((lr0 + 3 < vlimit) ? v3 : 0.f);
                p0 = f2bf(v0); p1 = f2bf(v1); p2 = f2bf(v2); p3 = f2bf(v3);
            }
            const int grow = row_base + rbase + qt * 4;   // multiple of 4
            unsigned int* p = reinterpret_cast<unsigned int*>(
                reinterpret_cast<char*>(X2) + col * 300 + grow * 2);
            p[0] = (unsigned int)p0 | ((unsigned int)p1 << 16);
            p[1] = (unsigned int)p2 | ((unsigned int)p3 << 16);
        }

        // L2: gather A2 frags from X2 (stride 150 -> conflict-free), 14 MFMA
        short8v a2[2];
#pragma unroll
        for (int kt = 0; kt < 2; ++kt) {
#pragma unroll
            for (int e = 0; e < 8; ++e) {
                const int k = kt * 32 + qt * 8 + e;
                a2[kt][e] = (short)X2[k * 150 + (row_base + rbase + m)];
            }
        }
        float4v C2[7];
#pragma unroll
        for (int nt = 0; nt < 7; ++nt) {
            C2[nt] = __builtin_amdgcn_mfma_f32_16x16x32_bf16(a2[0], B2g[0][nt], (float4v){0.f, 0.f, 0.f, 0.f}, 0, 0, 0);
            C2[nt] = __builtin_amdgcn_mfma_f32_16x16x32_bf16(a2[1], B2g[1][nt], C2[nt], 0, 0, 0);
        }

        // epilogue: tanh + masked column partial sums
#pragma unroll
        for (int nt = 0; nt < 7; ++nt) {
            const int col = nt * 16 + m;
            const int lr0 = rbase + qt * 4;
#pragma unroll
            for (int r = 0; r < 4; ++r) {
                float g = fast_tanh(C2[nt][r] + b2v[nt]);
                psumr[nt] += (col < 100 && (lr0 + r) < vlimit) ? g : 0.f;
            }
        }
    }

    // ---------------- cross-quarter reduce, deterministic cross-wave merge ----------------
#pragma unroll
    for (int nt = 0; nt < 7; ++nt) {
        float v = psumr[nt];
        v += __shfl_xor(v, 16);
        v += __shfl_xor(v, 32);
        if (lane < 16) psum[wave][nt * 16 + lane] = v;
    }
#pragma unroll
    for (int nt = 0; nt < 4; ++nt) {
        float v = s2r[nt];
        v += __shfl_xor(v, 16);
        v += __shfl_xor(v, 32);
        if (lane < 16) s2w[wave][nt * 16 + lane] = v;
    }
    __syncthreads();
    float ps = 0.f;
    if (tid < 112) ps = psum[0][tid] + psum[1][tid] + psum[2][tid] + psum[3][tid];
    if (tid < 64) S2m[tid] = s2w[0][tid] + s2w[1][tid] + s2w[2][tid] + s2w[3][tid];
    __syncthreads();
    if (tid < 100) {
        const int cm = (tid < 50) ? tid : (tid - 50);
        out_res[b * 100 + tid] = (ps + S2m[cm]) * (0.2f / 138.0f);
    }
}

extern "C" void kernel_launch(void* const* d_in, const int* in_sizes, int n_in,
                              void* d_out, int out_size, void* d_ws, size_t ws_size,
                              hipStream_t stream) {
    const float* coord  = (const float*)d_in[0];
    const int*   atype  = (const int*)d_in[1];
    const int*   nlist  = (const int*)d_in[2];
    const float* mean   = (const float*)d_in[3];
    const float* stddev = (const float*)d_in[4];
    const float* w0 = (const float*)d_in[5];
    const float* b0 = (const float*)d_in[6];
    const float* w1 = (const float*)d_in[7];
    const float* b1 = (const float*)d_in[8];
    const float* w2 = (const float*)d_in[9];
    const float* b2 = (const float*)d_in[10];

    __hip_bfloat16* wsbf = (__hip_bfloat16*)d_ws;
    float* out_res = (float*)d_out;                 // [2][4096][100]
    float* out_sw  = out_res + NF * NLOC * 100;     // [2][4096][138]

    hipLaunchKernelGGL(prep_weights, dim3(72), dim3(256), 0, stream, w1, w2, wsbf);
    hipLaunchKernelGGL(descr_mfma, dim3(NF * NLOC), dim3(256), 0, stream,
                       coord, atype, nlist, mean, stddev, w0, b0, b1, b2,
                       wsbf /*B1f*/, wsbf + 4096 /*B2f*/, out_res, out_sw);
}

// Round 4
// 123.298 us; speedup vs baseline: 3.9044x; 1.0232x over previous
//
#include <hip/hip_runtime.h>
#include <hip/hip_bf16.h>

typedef unsigned short u16;
typedef __attribute__((ext_vector_type(8))) short short8v;
typedef __attribute__((ext_vector_type(4))) float float4v;

#define NF 2
#define NLOC 4096
#define NALL 8192
#define NNEI_ 138
#define ATOMS_PER_BLOCK 4

__device__ __forceinline__ float fast_tanh(float a) {
#if __has_builtin(__builtin_amdgcn_exp2f) && __has_builtin(__builtin_amdgcn_rcpf)
    float t = __builtin_amdgcn_exp2f(a * 2.885390081777927f);  // exp(2a)
    return 1.0f - 2.0f * __builtin_amdgcn_rcpf(t + 1.0f);
#else
    float t = exp2f(a * 2.885390081777927f);
    return 1.0f - 2.0f / (t + 1.0f);
#endif
}

__device__ __forceinline__ u16 f2bf(float x) {
    __hip_bfloat16 h = __float2bfloat16(x);
    return *reinterpret_cast<u16*>(&h);
}

__device__ __forceinline__ float bf2f(u16 b) {
    union { unsigned int u; float f; } c;
    c.u = ((unsigned int)b) << 16;
    return c.f;
}

// Pack weights into MFMA B-fragment order (bf16), zero-padded.
// B1: [2 types][4 ntiles][64 lanes][8 elems]   (K=25->32, N=50->64)
// B2: [2 types][2 ktiles][7 ntiles][64][8]     (K=50->64, N=100->112)
__global__ void prep_weights(const float* __restrict__ w1, const float* __restrict__ w2,
                             __hip_bfloat16* __restrict__ wsbf) {
    int i = threadIdx.x + blockIdx.x * blockDim.x;
    if (i < 4096) {
        int e = i & 7, lane = (i >> 3) & 63, nt = (i >> 9) & 3, t = i >> 11;
        int k = (lane >> 4) * 8 + e, j = nt * 16 + (lane & 15);
        float v = (k < 25 && j < 50) ? w1[t * 1250 + k * 50 + j] : 0.0f;
        wsbf[i] = __float2bfloat16(v);
    } else if (i < 4096 + 14336) {
        int j2 = i - 4096;
        int e = j2 & 7, lane = (j2 >> 3) & 63;
        int q = j2 >> 9;
        int nt = q % 7, kt = (q / 7) & 1, t = q / 14;
        int k = kt * 32 + (lane >> 4) * 8 + e, j = nt * 16 + (lane & 15);
        float v = (k < 50 && j < 100) ? w2[t * 5000 + k * 100 + j] : 0.0f;
        wsbf[4096 + j2] = __float2bfloat16(v);
    }
}

// Block = ATOMS_PER_BLOCK atoms, processed sequentially.
// Rows: 0-47 = type0 neighbors 0-45 (+2 pad), wave 0.
//       48-143 = type1 neighbors 46-137 (+4 pad), waves 1-3 (32 rows each).
__global__ __launch_bounds__(256, 2) void descr_mfma(
    const float* __restrict__ coord, const int* __restrict__ atype,
    const int* __restrict__ nlist, const float* __restrict__ mean,
    const float* __restrict__ stddev,
    const float* __restrict__ w0, const float* __restrict__ b0,
    const float* __restrict__ b1, const float* __restrict__ b2,
    const __hip_bfloat16* __restrict__ B1f, const __hip_bfloat16* __restrict__ B2f,
    float* __restrict__ out_res, float* __restrict__ out_sw)
{
    __shared__ __align__(16) u16 X[144 * 32];   // row-major, 16B-slot XOR swizzle (as round 2)
    __shared__ __align__(8)  u16 X2[64 * 150];  // col-major, stride 150 (bank-perfect A2 reads)
    __shared__ float psum[4][112];
    __shared__ float s2w[4][64];
    __shared__ float S2m[64];

    const int tid = threadIdx.x, wave = tid >> 6, lane = tid & 63;
    const int t = wave ? 1 : 0;
    const int row_base = wave ? (48 + 32 * (wave - 1)) : 0;
    const int n_rows = wave ? 32 : 48;
    const int mtiles = wave ? 2 : 3;
    const int vlimit = (wave == 0) ? 46 : ((wave == 3) ? 28 : 32);
    const int m = lane & 15, qt = lane >> 4;

    // ---------------- per-type constants & B fragments (hoisted over atoms) ----------------
    float b1v[4], b2v[7];
    int slotb[4], obyte[4];  // residual element address pieces: cm>>3, (cm&7)*2
#pragma unroll
    for (int nt = 0; nt < 4; ++nt) {
        int col = nt * 16 + m;
        b1v[nt] = (col < 50) ? b1[t * 50 + col] : 0.0f;
        int cm = (col < 25) ? col : ((col < 50) ? (col - 25) : 0);
        slotb[nt] = cm >> 3;
        obyte[nt] = (cm & 7) * 2;
    }
#pragma unroll
    for (int nt = 0; nt < 7; ++nt) {
        int col = nt * 16 + m;
        b2v[nt] = (col < 100) ? b2[t * 100 + col] : 0.0f;
    }
    short8v B1g[4], B2g[2][7];
#pragma unroll
    for (int nt = 0; nt < 4; ++nt)
        B1g[nt] = *(const short8v*)(B1f + ((t * 4 + nt) * 64 + lane) * 8);
#pragma unroll
    for (int kt = 0; kt < 2; ++kt)
#pragma unroll
        for (int nt = 0; nt < 7; ++nt)
            B2g[kt][nt] = *(const short8v*)(B2f + (((t * 2 + kt) * 7 + nt) * 64 + lane) * 8);

    const float* w0t = w0 + t * 25;
    const float* b0t = b0 + t * 25;

#pragma unroll 1
    for (int ai = 0; ai < ATOMS_PER_BLOCK; ++ai) {
        const int b = blockIdx.x * ATOMS_PER_BLOCK + ai;
        const int f = b >> 12, il = b & 4095;

        const int aty = atype[f * NALL + il];
        const float cx = coord[(f * NALL + il) * 3 + 0];
        const float cy = coord[(f * NALL + il) * 3 + 1];
        const float cz = coord[(f * NALL + il) * 3 + 2];

        // ---------------- phase A: s, sw, X staging ----------------
        {
            float s = 0.0f;
            const int row = row_base + lane;
            if (lane < vlimit) {
                const int n = wave ? (row - 2) : row;   // neighbor slot 0..137
                int jn = nlist[b * NNEI_ + n];
                float sw = 0.0f, env = 0.0f;
                if (jn >= 0) {
                    float dx = coord[(f * NALL + jn) * 3 + 0] - cx;
                    float dy = coord[(f * NALL + jn) * 3 + 1] - cy;
                    float dz = coord[(f * NALL + jn) * 3 + 2] - cz;
                    float len = sqrtf(dx * dx + dy * dy + dz * dz);
                    float uu = (len - 0.5f) * (1.0f / 5.5f);
                    float vv = uu * uu * uu * (uu * (-6.0f * uu + 15.0f) - 10.0f) + 1.0f;
                    sw = (len <= 0.5f) ? 1.0f : ((len >= 6.0f) ? 0.0f : vv);
                    env = sw / len;
                }
                out_sw[b * NNEI_ + n] = sw;
                s = (env - mean[aty * NNEI_ + n]) / stddev[aty * NNEI_ + n];
            }
            if (lane < n_rows) {
                unsigned int xp[16];
#pragma unroll
                for (int kk = 0; kk < 13; ++kk) {
                    float v0 = fast_tanh(s * w0t[2 * kk] + b0t[2 * kk]);
                    float v1 = (2 * kk + 1 < 25) ? fast_tanh(s * w0t[2 * kk + 1] + b0t[2 * kk + 1]) : 0.0f;
                    xp[kk] = (unsigned int)f2bf(v0) | ((unsigned int)f2bf(v1) << 16);
                }
                xp[13] = 0; xp[14] = 0; xp[15] = 0;
#pragma unroll
                for (int sl = 0; sl < 4; ++sl) {
                    int slot = sl ^ (row & 3);
                    uint4 v = make_uint4(xp[4 * sl], xp[4 * sl + 1], xp[4 * sl + 2], xp[4 * sl + 3]);
                    *reinterpret_cast<uint4*>(reinterpret_cast<char*>(X) + row * 64 + slot * 16) = v;
                }
            }
        }

        float psumr[7] = {0, 0, 0, 0, 0, 0, 0};
        float s2r[4] = {0, 0, 0, 0};

        // ---------------- main loop over M-tiles (wave-local) ----------------
#pragma unroll
        for (int mt = 0; mt < 3; ++mt) {
            if (mt >= mtiles) break;
            const int rbase = mt * 16;

            // L1: A-frag from X (swizzled), 4 MFMA
            const int arow = row_base + rbase + m;
            const int slot = qt ^ (arow & 3);
            short8v a1 = *(const short8v*)(reinterpret_cast<const char*>(X) + arow * 64 + slot * 16);
            float4v C1[4];
#pragma unroll
            for (int nt = 0; nt < 4; ++nt)
                C1[nt] = __builtin_amdgcn_mfma_f32_16x16x32_bf16(a1, B1g[nt], (float4v){0.f, 0.f, 0.f, 0.f}, 0, 0, 0);

            // x2 = tanh(C1+b1) + x (x read back from swizzled X as bf16), stage to X2
            // C/D row = qt*4 + r; since (row_base+rbase+qt*4) % 4 == 0, R&3 == r.
            const char* Xrb = reinterpret_cast<const char*>(X) + (row_base + rbase + qt * 4) * 64;
#pragma unroll
            for (int nt = 0; nt < 4; ++nt) {
                const int col = nt * 16 + m;
                float v0 = 0.f, v1 = 0.f, v2 = 0.f, v3 = 0.f;
                if (col < 50) {
                    float x0 = bf2f(*(const u16*)(Xrb + 0 * 64 + ((slotb[nt] ^ 0) << 4) + obyte[nt]));
                    float x1 = bf2f(*(const u16*)(Xrb + 1 * 64 + ((slotb[nt] ^ 1) << 4) + obyte[nt]));
                    float x2_ = bf2f(*(const u16*)(Xrb + 2 * 64 + ((slotb[nt] ^ 2) << 4) + obyte[nt]));
                    float x3 = bf2f(*(const u16*)(Xrb + 3 * 64 + ((slotb[nt] ^ 3) << 4) + obyte[nt]));
                    v0 = fast_tanh(C1[nt][0] + b1v[nt]) + x0;
                    v1 = fast_tanh(C1[nt][1] + b1v[nt]) + x1;
                    v2 = fast_tanh(C1[nt][2] + b1v[nt]) + x2_;
                    v3 = fast_tanh(C1[nt][3] + b1v[nt]) + x3;
                }
                const int lr0 = rbase + qt * 4;
                s2r[nt] += ((lr0 + 0 < vlimit) ? v0 : 0.f) + ((lr0 + 1 < vlimit) ? v1 : 0.f) +
                           ((lr0 + 2 < vlimit) ? v2 : 0.f) + ((lr0 + 3 < vlimit) ? v3 : 0.f);
                const int grow = row_base + rbase + qt * 4;   // multiple of 4
                unsigned int* p = reinterpret_cast<unsigned int*>(
                    reinterpret_cast<char*>(X2) + col * 300 + grow * 2);
                p[0] = (unsigned int)f2bf(v0) | ((unsigned int)f2bf(v1) << 16);
                p[1] = (unsigned int)f2bf(v2) | ((unsigned int)f2bf(v3) << 16);
            }

            // L2: gather A2 frags from X2 (stride 150 -> conflict-free), 14 MFMA
            short8v a2[2];
#pragma unroll
            for (int kt = 0; kt < 2; ++kt) {
#pragma unroll
                for (int e = 0; e < 8; ++e) {
                    const int k = kt * 32 + qt * 8 + e;
                    a2[kt][e] = (short)X2[k * 150 + (row_base + rbase + m)];
                }
            }
            float4v C2[7];
#pragma unroll
            for (int nt = 0; nt < 7; ++nt) {
                C2[nt] = __builtin_amdgcn_mfma_f32_16x16x32_bf16(a2[0], B2g[0][nt], (float4v){0.f, 0.f, 0.f, 0.f}, 0, 0, 0);
                C2[nt] = __builtin_amdgcn_mfma_f32_16x16x32_bf16(a2[1], B2g[1][nt], C2[nt], 0, 0, 0);
            }

            // epilogue: tanh + masked column partial sums
#pragma unroll
            for (int nt = 0; nt < 7; ++nt) {
                const int col = nt * 16 + m;
                const int lr0 = rbase + qt * 4;
#pragma unroll
                for (int r = 0; r < 4; ++r) {
                    float g = fast_tanh(C2[nt][r] + b2v[nt]);
                    psumr[nt] += (col < 100 && (lr0 + r) < vlimit) ? g : 0.f;
                }
            }
        }

        // ---------------- cross-quarter reduce, deterministic cross-wave merge ----------------
#pragma unroll
        for (int nt = 0; nt < 7; ++nt) {
            float v = psumr[nt];
            v += __shfl_xor(v, 16);
            v += __shfl_xor(v, 32);
            if (lane < 16) psum[wave][nt * 16 + lane] = v;
        }
#pragma unroll
        for (int nt = 0; nt < 4; ++nt) {
            float v = s2r[nt];
            v += __shfl_xor(v, 16);
            v += __shfl_xor(v, 32);
            if (lane < 16) s2w[wave][nt * 16 + lane] = v;
        }
        __syncthreads();
        float ps = 0.f;
        if (tid < 112) ps = psum[0][tid] + psum[1][tid] + psum[2][tid] + psum[3][tid];
        if (tid < 64) S2m[tid] = s2w[0][tid] + s2w[1][tid] + s2w[2][tid] + s2w[3][tid];
        __syncthreads();
        if (tid < 100) {
            const int cm = (tid < 50) ? tid : (tid - 50);
            out_res[b * 100 + tid] = (ps + S2m[cm]) * (0.2f / 138.0f);
        }
    }
}

extern "C" void kernel_launch(void* const* d_in, const int* in_sizes, int n_in,
                              void* d_out, int out_size, void* d_ws, size_t ws_size,
                              hipStream_t stream) {
    const float* coord  = (const float*)d_in[0];
    const int*   atype  = (const int*)d_in[1];
    const int*   nlist  = (const int*)d_in[2];
    const float* mean   = (const float*)d_in[3];
    const float* stddev = (const float*)d_in[4];
    const float* w0 = (const float*)d_in[5];
    const float* b0 = (const float*)d_in[6];
    const float* w1 = (const float*)d_in[7];
    const float* b1 = (const float*)d_in[8];
    const float* w2 = (const float*)d_in[9];
    const float* b2 = (const float*)d_in[10];

    __hip_bfloat16* wsbf = (__hip_bfloat16*)d_ws;
    float* out_res = (float*)d_out;                 // [2][4096][100]
    float* out_sw  = out_res + NF * NLOC * 100;     // [2][4096][138]

    hipLaunchKernelGGL(prep_weights, dim3(72), dim3(256), 0, stream, w1, w2, wsbf);
    hipLaunchKernelGGL(descr_mfma, dim3((NF * NLOC) / ATOMS_PER_BLOCK), dim3(256), 0, stream,
                       coord, atype, nlist, mean, stddev, w0, b0, b1, b2,
                       wsbf /*B1f*/, wsbf + 4096 /*B2f*/, out_res, out_sw);
}